// Round 8
// baseline (367.574 us; speedup 1.0000x reference)
//
#include <hip/hip_runtime.h>
#include <math.h>

// Problem constants
#define S 192
#define H 64
#define NH 8           // b*n = 1*8
#define SC 0.125f
#define FILLV (-1000000.0f)

// ---------------- wave (64-lane) reductions ----------------
__device__ __forceinline__ float wave_max(float v) {
#pragma unroll
  for (int m = 32; m; m >>= 1) v = fmaxf(v, __shfl_xor(v, m));
  return v;
}
__device__ __forceinline__ float wave_sum(float v) {
#pragma unroll
  for (int m = 32; m; m >>= 1) v += __shfl_xor(v, m);
  return v;
}

// =====================================================================
// K1: GEMMs (kk, qk, qkT) + silu(v1) + per-t stats (mt, St, Aw).
// (unchanged from R7 — validated)
// =====================================================================
__global__ __launch_bounds__(256) void k1_kernel(
    const float* __restrict__ q, const float* __restrict__ k1,
    const float* __restrict__ k2, const float* __restrict__ v1,
    float* __restrict__ kk, float* __restrict__ qk, float* __restrict__ qkT,
    float* __restrict__ sv1,
    float* __restrict__ mt, float* __restrict__ St, float* __restrict__ Aw) {
  __shared__ float smem[12996];   // union: GEMM uses 4160; stats uses all
  int b = blockIdx.x;
  int tid = threadIdx.x;

  if (b < 864) {                                    // ---- GEMM tiles ----
    int p = b / 288, bb = b % 288;
    int n = bb / 36, rem = bb % 36;
    int rt = (rem / 6) * 32, ct = (rem % 6) * 32;
    const float *Abase, *Bbase;
    float* out;
    if (p == 0)      { Abase = k1; Bbase = k2; out = kk; }
    else if (p == 1) { Abase = k2; Bbase = q;  out = qk; }
    else             { Abase = q;  Bbase = k2; out = qkT; }
    Abase += n * S * H; Bbase += n * S * H; out += n * S * S;

    float* As = smem;            // [32][65]
    float* Bs = smem + 2080;     // [32][65]
    for (int i = tid; i < 32 * 64; i += 256) {
      int r = i >> 6, h = i & 63;
      As[r * 65 + h] = Abase[(rt + r) * H + h];
      Bs[r * 65 + h] = Bbase[(ct + r) * H + h];
    }
    __syncthreads();
    int r0 = (tid / 16) * 2, c0 = (tid % 16) * 2;
    float a00 = 0.f, a01 = 0.f, a10 = 0.f, a11 = 0.f;
#pragma unroll
    for (int h = 0; h < 64; ++h) {
      float x0 = As[r0 * 65 + h], x1 = As[(r0 + 1) * 65 + h];
      float y0 = Bs[c0 * 65 + h], y1 = Bs[(c0 + 1) * 65 + h];
      a00 += x0 * y0; a01 += x0 * y1; a10 += x1 * y0; a11 += x1 * y1;
    }
    out[(rt + r0) * S + ct + c0]         = a00;
    out[(rt + r0) * S + ct + c0 + 1]     = a01;
    out[(rt + r0 + 1) * S + ct + c0]     = a10;
    out[(rt + r0 + 1) * S + ct + c0 + 1] = a11;

  } else if (b < 960) {                             // ---- silu(v1) ----
    int i = (b - 864) * 256 + tid;                  // 24576 float4
    const float4* v4 = (const float4*)v1;
    float4 x = v4[i];
    float4 y;
    y.x = x.x / (1.f + expf(-x.x));
    y.y = x.y / (1.f + expf(-x.y));
    y.z = x.z / (1.f + expf(-x.z));
    y.w = x.w / (1.f + expf(-x.w));
    ((float4*)sv1)[i] = y;

  } else {                                          // ---- stats (n,t) ----
    int idx = b - 960;
    int n = idx / S, t = idx % S;
    int wv = tid >> 6, lane = tid & 63;
    float* k1s  = smem;                 // [192][65] staged k1 rows
    float* k2t  = smem + 12480;         // [64]
    float* w    = smem + 12544;         // [192]
    float* red  = smem + 12736;         // [4]
    float* part = smem + 12740;         // [4][64]

    const float* k1b = k1 + n * S * H;
    if (tid < 64) k2t[tid] = k2[(n * S + t) * H + tid];
    int nel = (t + 1) * 64;
    for (int i = tid; i < nel; i += 256) {
      int r = i >> 6, h = i & 63;
      k1s[r * 65 + h] = k1b[i];
    }
    __syncthreads();

    // GEMV: kk[s][t] = dot(k1[s], k2[t]) for s = tid <= t
    if (tid <= t) {
      float sc = 0.f;
#pragma unroll
      for (int h = 0; h < 64; ++h) sc += k1s[tid * 65 + h] * k2t[h];
      w[tid] = sc;
    }
    __syncthreads();

    float lm = -3.4e38f;
    if (tid <= t) lm = SC * w[tid];
    lm = wave_max(lm);
    if (lane == 0) red[wv] = lm;
    __syncthreads();
    float m = fmaxf(fmaxf(red[0], red[1]), fmaxf(red[2], red[3]));
    __syncthreads();                    // red reuse

    float ls = 0.f;
    if (tid <= t) {
      float e = expf(SC * w[tid] - m);
      w[tid] = e;
      ls = e;
    }
    ls = wave_sum(ls);
    if (lane == 0) red[wv] = ls;
    __syncthreads();
    float Ssum = red[0] + red[1] + red[2] + red[3];
    if (tid == 0) { mt[n * S + t] = m; St[n * S + t] = Ssum; }

    // Aw[t,h] = sum_{s<=t} w[s]*silu(v1[s,h]); 4 waves split s, lane = h
    const float* v1h = v1 + n * S * H + lane;
    float acc = 0.f;
    for (int s = wv; s <= t; s += 4) {
      float x = v1h[s * H];
      acc += w[s] * (x / (1.f + expf(-x)));
    }
    part[wv * 64 + lane] = acc;
    __syncthreads();
    if (wv == 0)
      Aw[(n * S + t) * H + lane] =
          part[lane] + part[64 + lane] + part[128 + lane] + part[192 + lane];
  }
}

// =====================================================================
// out kernel: per (n,q) — 6 waves (identical logic to R7's K2 out phase)
// =====================================================================
__global__ __launch_bounds__(384) void out_kernel(
    const float* __restrict__ qkT, const float* __restrict__ v2,
    const float* __restrict__ mt, const float* __restrict__ St,
    const float* __restrict__ Aw,
    float* __restrict__ z, float* __restrict__ Mout) {
  __shared__ float e[S];
  __shared__ float red[6];
  __shared__ float part[6 * 64];
  int idx = blockIdx.x;
  int tid = threadIdx.x;
  int n = idx / S, qq = idx % S;
  int wv = tid >> 6, lane = tid & 63;
  const float* qkr = qkT + n * S * S + qq * S;    // qkr[t] = qk[t][q]
  const float* mtp = mt + n * S;
  const float* Stp = St + n * S;

  float lm = -3.4e38f;
  if (tid <= qq) lm = SC * qkr[tid] + mtp[tid];   // one t per thread (384>=192)
  lm = wave_max(lm);
  if (lane == 0) red[wv] = lm;
  __syncthreads();
  float M0 = red[0];
#pragma unroll
  for (int i = 1; i < 6; ++i) M0 = fmaxf(M0, red[i]);
  __syncthreads();                                // red reuse

  float ls = 0.f;
  if (tid <= qq) {
    float ev = expf(SC * qkr[tid] + mtp[tid] - M0);
    e[tid] = ev;
    ls = ev * Stp[tid];
  }
  ls = wave_sum(ls);
  if (lane == 0) red[wv] = ls;
  __syncthreads();                                // also fences e[]
  float D = red[0] + red[1] + red[2] + red[3] + red[4] + red[5];
  if (tid == 0) Mout[n * S + qq] = M0 + logf(D + 0.01f);

  const float* vh = v2 + n * S * H + lane;
  const float* Ah = Aw + n * S * H + lane;
  float acc = 0.f;
  for (int t = wv; t <= qq; t += 6) acc += e[t] * vh[t * H] * Ah[t * H];
  part[wv * 64 + lane] = acc;
  __syncthreads();
  if (wv == 0) {
    float zsum = part[lane] + part[64 + lane] + part[128 + lane] +
                 part[192 + lane] + part[256 + lane] + part[320 + lane];
    z[(n * S + qq) * H + lane] = zsum / D;
  }
}

// =====================================================================
// score_flat: fill-style flat stream. One thread = one float4 of score.
// Monotone global index -> address mapping, like fillBufferAligned.
// 14155776 float4 total = 27648 blocks x 512.
// =====================================================================
__global__ __launch_bounds__(512) void score_flat(
    const float* __restrict__ kk, const float* __restrict__ qk,
    float* __restrict__ score) {
  int i = blockIdx.x * 512 + threadIdx.x;       // float4 index
  int j = i % 48;                                // q-quad within row
  int r = i / 48;                                // (n*192+s)*192 + t
  int t = r % 192;
  int ns = r / 192;                              // n*192+s
  int s = ns % 192;
  float4 v;
  if (t < s) {
    v = make_float4(FILLV, FILLV, FILLV, FILLV);
  } else {
    float kv = kk[ns * 192 + t];
    float4 qv = ((const float4*)qk)[(ns / 192) * 9216 + t * 48 + j];
    int q0 = 4 * j;
    v.x = (t > q0)     ? FILLV : kv + qv.x;
    v.y = (t > q0 + 1) ? FILLV : kv + qv.y;
    v.z = (t > q0 + 2) ? FILLV : kv + qv.z;
    v.w = (t > q0 + 3) ? FILLV : kv + qv.w;
  }
  ((float4*)score)[i] = v;
}

// =====================================================================
// vg_flat: fill-style flat stream. One thread = one float4 of v_gated.
// 4718592 float4 total = 9216 blocks x 512.
// =====================================================================
__global__ __launch_bounds__(512) void vg_flat(
    const float* __restrict__ sv1, const float* __restrict__ v2,
    float* __restrict__ vg) {
  int i = blockIdx.x * 512 + threadIdx.x;       // float4 index
  int j = i % 16;                                // h-quad
  int r = i / 16;                                // (n*192+s)*192 + t
  int t = r % 192;
  int ns = r / 192;                              // n*192+s
  int n = ns / 192;
  float4 a = ((const float4*)sv1)[ns * 16 + j];
  float4 b = ((const float4*)v2)[(n * 192 + t) * 16 + j];
  ((float4*)vg)[i] = make_float4(a.x * b.x, a.y * b.y, a.z * b.z, a.w * b.w);
}

extern "C" void kernel_launch(void* const* d_in, const int* in_sizes, int n_in,
                              void* d_out, int out_size, void* d_ws, size_t ws_size,
                              hipStream_t stream) {
  const float* q  = (const float*)d_in[0];
  const float* k1 = (const float*)d_in[1];
  const float* k2 = (const float*)d_in[2];
  const float* v1 = (const float*)d_in[3];
  const float* v2 = (const float*)d_in[4];
  float* out = (float*)d_out;

  // Output layout (concatenated flat, return order): z, pre_score, v_gated, M
  float* z     = out;                                  // 8*192*64       = 98304
  float* score = out + 98304;                          // 8*192*192*192  = 56623104
  float* vg    = out + 98304 + 56623104;               // 8*192*192*64   = 18874368
  float* Mout  = out + 98304 + 56623104 + 18874368;    // 8*192          = 1536

  // Workspace layout (floats)
  float* ws   = (float*)d_ws;
  float* kk   = ws;                  // 294912
  float* qk   = ws + 294912;         // 294912
  float* qkT  = ws + 589824;         // 294912
  float* sv1  = ws + 884736;         // 98304
  float* mt   = ws + 983040;         // 1536
  float* St   = ws + 984576;         // 1536
  float* Aw   = ws + 986112;         // 98304  -> total ~4.3 MB

  k1_kernel<<<dim3(2496), dim3(256), 0, stream>>>(q, k1, k2, v1, kk, qk, qkT,
                                                  sv1, mt, St, Aw);
  out_kernel<<<dim3(NH * S), dim3(384), 0, stream>>>(qkT, v2, mt, St, Aw, z, Mout);
  score_flat<<<dim3(27648), dim3(512), 0, stream>>>(kk, qk, score);
  vg_flat<<<dim3(9216), dim3(512), 0, stream>>>(sv1, v2, vg);
}

// Round 10
// 351.264 us; speedup vs baseline: 1.0464x; 1.0464x over previous
//
#include <hip/hip_runtime.h>
#include <math.h>

// Problem constants
#define S 192
#define H 64
#define NH 8           // b*n = 1*8
#define SC 0.125f
#define FILLV (-1000000.0f)

// ---------------- wave (64-lane) reductions ----------------
__device__ __forceinline__ float wave_max(float v) {
#pragma unroll
  for (int m = 32; m; m >>= 1) v = fmaxf(v, __shfl_xor(v, m));
  return v;
}
__device__ __forceinline__ float wave_sum(float v) {
#pragma unroll
  for (int m = 32; m; m >>= 1) v += __shfl_xor(v, m);
  return v;
}

// =====================================================================
// K1: GEMMs (kk, qk, qkT) + silu(v1) + per-t stats (mt, St, Aw).
// (unchanged from R7/R8 — validated)
//   blocks 0..287    : kk  = k1*k2^T  [s][t]
//   blocks 288..575  : qk  = k2*q^T   [t][q]
//   blocks 576..863  : qkT = q*k2^T   [q][t]
//   blocks 864..959  : sv1 = silu(v1)
//   blocks 960..2495 : stats per (n,t)
// =====================================================================
__global__ __launch_bounds__(256) void k1_kernel(
    const float* __restrict__ q, const float* __restrict__ k1,
    const float* __restrict__ k2, const float* __restrict__ v1,
    float* __restrict__ kk, float* __restrict__ qk, float* __restrict__ qkT,
    float* __restrict__ sv1,
    float* __restrict__ mt, float* __restrict__ St, float* __restrict__ Aw) {
  __shared__ float smem[12996];   // union: GEMM uses 4160; stats uses all
  int b = blockIdx.x;
  int tid = threadIdx.x;

  if (b < 864) {                                    // ---- GEMM tiles ----
    int p = b / 288, bb = b % 288;
    int n = bb / 36, rem = bb % 36;
    int rt = (rem / 6) * 32, ct = (rem % 6) * 32;
    const float *Abase, *Bbase;
    float* out;
    if (p == 0)      { Abase = k1; Bbase = k2; out = kk; }
    else if (p == 1) { Abase = k2; Bbase = q;  out = qk; }
    else             { Abase = q;  Bbase = k2; out = qkT; }
    Abase += n * S * H; Bbase += n * S * H; out += n * S * S;

    float* As = smem;            // [32][65]
    float* Bs = smem + 2080;     // [32][65]
    for (int i = tid; i < 32 * 64; i += 256) {
      int r = i >> 6, h = i & 63;
      As[r * 65 + h] = Abase[(rt + r) * H + h];
      Bs[r * 65 + h] = Bbase[(ct + r) * H + h];
    }
    __syncthreads();
    int r0 = (tid / 16) * 2, c0 = (tid % 16) * 2;
    float a00 = 0.f, a01 = 0.f, a10 = 0.f, a11 = 0.f;
#pragma unroll
    for (int h = 0; h < 64; ++h) {
      float x0 = As[r0 * 65 + h], x1 = As[(r0 + 1) * 65 + h];
      float y0 = Bs[c0 * 65 + h], y1 = Bs[(c0 + 1) * 65 + h];
      a00 += x0 * y0; a01 += x0 * y1; a10 += x1 * y0; a11 += x1 * y1;
    }
    out[(rt + r0) * S + ct + c0]         = a00;
    out[(rt + r0) * S + ct + c0 + 1]     = a01;
    out[(rt + r0 + 1) * S + ct + c0]     = a10;
    out[(rt + r0 + 1) * S + ct + c0 + 1] = a11;

  } else if (b < 960) {                             // ---- silu(v1) ----
    int i = (b - 864) * 256 + tid;                  // 24576 float4
    const float4* v4 = (const float4*)v1;
    float4 x = v4[i];
    float4 y;
    y.x = x.x / (1.f + expf(-x.x));
    y.y = x.y / (1.f + expf(-x.y));
    y.z = x.z / (1.f + expf(-x.z));
    y.w = x.w / (1.f + expf(-x.w));
    ((float4*)sv1)[i] = y;

  } else {                                          // ---- stats (n,t) ----
    int idx = b - 960;
    int n = idx / S, t = idx % S;
    int wv = tid >> 6, lane = tid & 63;
    float* k1s  = smem;                 // [192][65] staged k1 rows
    float* k2t  = smem + 12480;         // [64]
    float* w    = smem + 12544;         // [192]
    float* red  = smem + 12736;         // [4]
    float* part = smem + 12740;         // [4][64]

    const float* k1b = k1 + n * S * H;
    if (tid < 64) k2t[tid] = k2[(n * S + t) * H + tid];
    int nel = (t + 1) * 64;
    for (int i = tid; i < nel; i += 256) {
      int r = i >> 6, h = i & 63;
      k1s[r * 65 + h] = k1b[i];
    }
    __syncthreads();

    // GEMV: kk[s][t] = dot(k1[s], k2[t]) for s = tid <= t
    if (tid <= t) {
      float sc = 0.f;
#pragma unroll
      for (int h = 0; h < 64; ++h) sc += k1s[tid * 65 + h] * k2t[h];
      w[tid] = sc;
    }
    __syncthreads();

    float lm = -3.4e38f;
    if (tid <= t) lm = SC * w[tid];
    lm = wave_max(lm);
    if (lane == 0) red[wv] = lm;
    __syncthreads();
    float m = fmaxf(fmaxf(red[0], red[1]), fmaxf(red[2], red[3]));
    __syncthreads();                    // red reuse

    float ls = 0.f;
    if (tid <= t) {
      float e = expf(SC * w[tid] - m);
      w[tid] = e;
      ls = e;
    }
    ls = wave_sum(ls);
    if (lane == 0) red[wv] = ls;
    __syncthreads();
    float Ssum = red[0] + red[1] + red[2] + red[3];
    if (tid == 0) { mt[n * S + t] = m; St[n * S + t] = Ssum; }

    // Aw[t,h] = sum_{s<=t} w[s]*silu(v1[s,h]); 4 waves split s, lane = h
    const float* v1h = v1 + n * S * H + lane;
    float acc = 0.f;
    for (int s = wv; s <= t; s += 4) {
      float x = v1h[s * H];
      acc += w[s] * (x / (1.f + expf(-x)));
    }
    part[wv * 64 + lane] = acc;
    __syncthreads();
    if (wv == 0)
      Aw[(n * S + t) * H + lane] =
          part[lane] + part[64 + lane] + part[128 + lane] + part[192 + lane];
  }
}

// =====================================================================
// K2 (merged): out phase first, then score stream, then v_gated stream.
//   blocks 0..1535        : out per (n,q) — 8 waves of 512
//   blocks 1536..29183    : score, flat fill-style (27648 blocks)
//   blocks 29184..38399   : v_gated, flat fill-style (9216 blocks)
// =====================================================================
__global__ __launch_bounds__(512) void k2_kernel(
    const float* __restrict__ kk, const float* __restrict__ qk,
    const float* __restrict__ qkT, const float* __restrict__ sv1,
    const float* __restrict__ v2,
    const float* __restrict__ mt, const float* __restrict__ St,
    const float* __restrict__ Aw,
    float* __restrict__ score, float* __restrict__ vg,
    float* __restrict__ z, float* __restrict__ Mout) {
  int b = blockIdx.x;
  int tid = threadIdx.x;

  if (b < 1536) {                                   // ---- out (n,q) ----
    __shared__ float e[S];
    __shared__ float red[8];
    __shared__ float part[8 * 64];
    int n = b / S, qq = b % S;
    int wv = tid >> 6, lane = tid & 63;
    const float* qkr = qkT + n * S * S + qq * S;    // qkr[t] = qk[t][q]
    const float* mtp = mt + n * S;
    const float* Stp = St + n * S;

    float lm = -3.4e38f;
    if (tid <= qq) lm = SC * qkr[tid] + mtp[tid];   // one t per thread
    lm = wave_max(lm);
    if (lane == 0) red[wv] = lm;
    __syncthreads();
    float M0 = red[0];
#pragma unroll
    for (int i = 1; i < 8; ++i) M0 = fmaxf(M0, red[i]);
    __syncthreads();                                // red reuse

    float ls = 0.f;
    if (tid <= qq) {
      float ev = expf(SC * qkr[tid] + mtp[tid] - M0);
      e[tid] = ev;
      ls = ev * Stp[tid];
    }
    ls = wave_sum(ls);
    if (lane == 0) red[wv] = ls;
    __syncthreads();                                // also fences e[]
    float D = 0.f;
#pragma unroll
    for (int i = 0; i < 8; ++i) D += red[i];
    if (tid == 0) Mout[n * S + qq] = M0 + logf(D + 0.01f);

    const float* vh = v2 + n * S * H + lane;
    const float* Ah = Aw + n * S * H + lane;
    float acc = 0.f;
    for (int t = wv; t <= qq; t += 8) acc += e[t] * vh[t * H] * Ah[t * H];
    part[wv * 64 + lane] = acc;
    __syncthreads();
    if (wv == 0) {
      float zsum = 0.f;
#pragma unroll
      for (int i = 0; i < 8; ++i) zsum += part[i * 64 + lane];
      z[(n * S + qq) * H + lane] = zsum / D;
    }

  } else if (b < 29184) {                           // ---- score ----
    int i = (b - 1536) * 512 + tid;                 // float4 index
    int j = i % 48;                                 // q-quad within row
    int r = i / 48;                                 // (n*192+s)*192 + t
    int t = r % 192;
    int ns = r / 192;                               // n*192+s
    int s = ns % 192;
    float4 v;
    if (t < s) {
      v = make_float4(FILLV, FILLV, FILLV, FILLV);
    } else {
      float kv = kk[ns * 192 + t];
      float4 qv = ((const float4*)qk)[(ns / 192) * 9216 + t * 48 + j];
      int q0 = 4 * j;
      v.x = (t > q0)     ? FILLV : kv + qv.x;
      v.y = (t > q0 + 1) ? FILLV : kv + qv.y;
      v.z = (t > q0 + 2) ? FILLV : kv + qv.z;
      v.w = (t > q0 + 3) ? FILLV : kv + qv.w;
    }
    ((float4*)score)[i] = v;

  } else {                                          // ---- v_gated ----
    int i = (b - 29184) * 512 + tid;                // float4 index
    int j = i % 16;                                 // h-quad
    int r = i / 16;                                 // (n*192+s)*192 + t
    int t = r % 192;
    int ns = r / 192;                               // n*192+s
    int n = ns / 192;
    float4 a = ((const float4*)sv1)[ns * 16 + j];
    float4 bv = ((const float4*)v2)[(n * 192 + t) * 16 + j];
    ((float4*)vg)[i] = make_float4(a.x * bv.x, a.y * bv.y, a.z * bv.z, a.w * bv.w);
  }
}

extern "C" void kernel_launch(void* const* d_in, const int* in_sizes, int n_in,
                              void* d_out, int out_size, void* d_ws, size_t ws_size,
                              hipStream_t stream) {
  const float* q  = (const float*)d_in[0];
  const float* k1 = (const float*)d_in[1];
  const float* k2 = (const float*)d_in[2];
  const float* v1 = (const float*)d_in[3];
  const float* v2 = (const float*)d_in[4];
  float* out = (float*)d_out;

  // Output layout (concatenated flat, return order): z, pre_score, v_gated, M
  float* z     = out;                                  // 8*192*64       = 98304
  float* score = out + 98304;                          // 8*192*192*192  = 56623104
  float* vg    = out + 98304 + 56623104;               // 8*192*192*64   = 18874368
  float* Mout  = out + 98304 + 56623104 + 18874368;    // 8*192          = 1536

  // Workspace layout (floats)
  float* ws   = (float*)d_ws;
  float* kk   = ws;                  // 294912
  float* qk   = ws + 294912;         // 294912
  float* qkT  = ws + 589824;         // 294912
  float* sv1  = ws + 884736;         // 98304
  float* mt   = ws + 983040;         // 1536
  float* St   = ws + 984576;         // 1536
  float* Aw   = ws + 986112;         // 98304  -> total ~4.3 MB

  k1_kernel<<<dim3(2496), dim3(256), 0, stream>>>(q, k1, k2, v1, kk, qk, qkT,
                                                  sv1, mt, St, Aw);
  k2_kernel<<<dim3(38400), dim3(512), 0, stream>>>(kk, qk, qkT, sv1, v2, mt, St,
                                                   Aw, score, vg, z, Mout);
}